// Round 4
// baseline (191.475 us; speedup 1.0000x reference)
//
#include <hip/hip_runtime.h>

#define PH 7
#define PW 7
#define NB 49
#define SSCALE 0.0625f
#define CC 256
#define HH 200
#define WW 200
#define HWSZ (HH * WW)
#define ILPC 4          // channels per thread

// 8-byte vector with 4-byte alignment: backend emits dwordx2 if unaligned
// access is supported, else splits into two dword loads (correct either way)
typedef float f2v __attribute__((ext_vector_type(2), aligned(4)));

__global__ __launch_bounds__(256) void roi_align_v4(
    const float* __restrict__ features, const float* __restrict__ rois,
    float* __restrict__ out, int total)
{
    int idx = blockIdx.x * 256 + threadIdx.x;
    if (idx >= total) return;

    int bin = idx % NB;          // const-divisor -> magic mul
    int rem = idx / NB;
    int cq  = rem & 63;          // channel quad 0..63
    int n   = rem >> 6;          // roi
    int ph  = bin / PW;
    int pw  = bin - ph * PW;

    const float* r = rois + (size_t)n * 5;
    int   b  = (int)r[0];
    float x1 = r[1] * SSCALE, y1 = r[2] * SSCALE;
    float x2 = r[3] * SSCALE, y2 = r[4] * SSCALE;
    float bw = fmaxf(x2 - x1, 1.f) * (1.f / PW);
    float bh = fmaxf(y2 - y1, 1.f) * (1.f / PH);

    // ---- y samples: row offsets + validity-folded weights ----
    int ry[2][2]; float wy[2][2];
    #pragma unroll
    for (int i = 0; i < 2; ++i) {
        float y  = y1 + ((float)ph + (i ? 0.75f : 0.25f)) * bh;
        bool  v  = (y >= -1.f) && (y <= (float)HH);
        float cy = fmaxf(y, 0.f);
        int   yl = min((int)cy, HH - 1);      // cy>=0 so cast == floor
        int   yh = min(yl + 1, HH - 1);
        float fy = (yl >= HH - 1) ? 0.f : (cy - (float)yl);
        wy[i][0] = v ? (1.f - fy) : 0.f;
        wy[i][1] = v ? fy : 0.f;
        ry[i][0] = yl * WW;
        ry[i][1] = yh * WW;
    }
    // ---- x samples: clamped pair-base + edge-shift flag ----
    int xb[2]; bool sh[2]; float wx[2][2];
    #pragma unroll
    for (int i = 0; i < 2; ++i) {
        float x  = x1 + ((float)pw + (i ? 0.75f : 0.25f)) * bw;
        bool  v  = (x >= -1.f) && (x <= (float)WW);
        float cx = fmaxf(x, 0.f);
        int   xl = min((int)cx, WW - 1);
        float fx = (xl >= WW - 1) ? 0.f : (cx - (float)xl);
        wx[i][0] = v ? (1.f - fx) : 0.f;
        wx[i][1] = v ? fx : 0.f;
        int base = min(xl, WW - 2);           // pair [base, base+1] in-bounds
        xb[i] = base;
        sh[i] = (xl != base);                 // true only at xl == W-1 (fx==0)
    }

    const float* fb = features + ((size_t)b * CC + (size_t)cq * ILPC) * HWSZ;

    float acc0 = 0.f, acc1 = 0.f, acc2 = 0.f, acc3 = 0.f;
    #pragma unroll
    for (int iy = 0; iy < 2; ++iy) {
        #pragma unroll
        for (int ix = 0; ix < 2; ++ix) {
            float w00 = wy[iy][0] * wx[ix][0];
            float w01 = wy[iy][0] * wx[ix][1];
            float w10 = wy[iy][1] * wx[ix][0];
            float w11 = wy[iy][1] * wx[ix][1];
            int oLo = ry[iy][0] + xb[ix];
            int oHi = ry[iy][1] + xb[ix];
            bool s  = sh[ix];
            #pragma unroll
            for (int ch = 0; ch < ILPC; ++ch) {
                const float* p = fb + (size_t)ch * HWSZ;
                f2v a = *(const f2v*)(p + oLo);   // [f[xl], f[xl+1]] (or shifted at edge)
                f2v q = *(const f2v*)(p + oHi);
                float v00 = s ? a.y : a.x;
                float v10 = s ? q.y : q.x;
                float contrib = w00 * v00 + w01 * a.y + w10 * v10 + w11 * q.y;
                if      (ch == 0) acc0 += contrib;
                else if (ch == 1) acc1 += contrib;
                else if (ch == 2) acc2 += contrib;
                else              acc3 += contrib;
            }
        }
    }

    size_t ob = ((size_t)n * CC + (size_t)cq * ILPC) * NB + bin;
    out[ob         ] = acc0 * 0.25f;
    out[ob +     NB] = acc1 * 0.25f;
    out[ob + 2 * NB] = acc2 * 0.25f;
    out[ob + 3 * NB] = acc3 * 0.25f;
}

extern "C" void kernel_launch(void* const* d_in, const int* in_sizes, int n_in,
                              void* d_out, int out_size, void* d_ws, size_t ws_size,
                              hipStream_t stream) {
    const float* features = (const float*)d_in[0];
    const float* rois     = (const float*)d_in[1];
    float*       out      = (float*)d_out;

    int N     = in_sizes[1] / 5;              // 512
    int total = N * (CC / ILPC) * NB;         // 512*64*49 = 1,605,632
    int grid  = (total + 255) / 256;          // 6272

    roi_align_v4<<<grid, 256, 0, stream>>>(features, rois, out, total);
}